// Round 9
// baseline (2517.185 us; speedup 1.0000x reference)
//
#include <hip/hip_runtime.h>
#include <hip/hip_bf16.h>
#include <hip/hip_cooperative_groups.h>

#define DD 32
#define GG 96   // 3*DD

typedef __attribute__((ext_vector_type(8))) short bf16x8;
typedef __attribute__((ext_vector_type(4))) float f32x4;

__device__ __forceinline__ float frcp(float x){ return __builtin_amdgcn_rcpf(x); }
__device__ __forceinline__ float fsig(float x){
    float e = __expf(-x);
    return frcp(1.0f + e);
}
__device__ __forceinline__ float ftanh(float x){
    float ax = fabsf(x);
    float e  = __expf(-2.0f * ax);
    float t  = (1.0f - e) * frcp(1.0f + e);
    return copysignf(t, x);
}
__device__ __forceinline__ short f2bf(float f){
    union { float f; unsigned u; } v; v.f = f;
    unsigned r = v.u + 0x7fffu + ((v.u >> 16) & 1u);   // RNE
    return (short)(r >> 16);
}
__device__ __forceinline__ float bf2f(short s){
    union { unsigned u; float f; } v; v.u = ((unsigned)(unsigned short)s) << 16;
    return v.f;
}
__device__ __forceinline__ void split2(float x, short& hi, short& lo){
    hi = f2bf(x);
    lo = f2bf(x - bf2f(hi));
}
__device__ __forceinline__ f32x4 splat4(float x){ f32x4 v = { x, x, x, x }; return v; }

#define MFMA3(acc, ah, al, bh, bl) do { \
    acc = __builtin_amdgcn_mfma_f32_16x16x32_bf16(ah, bh, acc, 0, 0, 0); \
    acc = __builtin_amdgcn_mfma_f32_16x16x32_bf16(al, bh, acc, 0, 0, 0); \
    acc = __builtin_amdgcn_mfma_f32_16x16x32_bf16(ah, bl, acc, 0, 0, 0); \
} while (0)

// ---------------- setup kernels ----------------

__global__ void zero_ints_kernel(int* a, int n){
    int i = blockIdx.x * blockDim.x + threadIdx.x;
    if (i < n) a[i] = 0;
}

__global__ void init_link_kernel(const float* __restrict__ cap, float* __restrict__ ls,
                                 short* __restrict__ lsbh, short* __restrict__ lsbl, int n_links){
    int i = blockIdx.x * blockDim.x + threadIdx.x;
    if (i >= n_links * DD) return;
    int l = i >> 5, d = i & 31;
    float v = (d == 0) ? cap[l] : 0.0f;
    ls[i] = v;
    short hi, lo; split2(v, hi, lo);
    lsbh[i] = hi; lsbl[i] = lo;
}

__global__ void init_path_kernel(const float* __restrict__ traffic, const float* __restrict__ packets,
                                 const float* __restrict__ tdp, float* __restrict__ ps, int n_paths){
    int i = blockIdx.x * blockDim.x + threadIdx.x;
    if (i >= n_paths * DD) return;
    int p = i >> 5, d = i & 31;
    float v = 0.0f;
    if (d == 0) v = traffic[p];
    else if (d == 1) v = packets[p];
    else if (d < 14) v = tdp[p * 12 + (d - 2)];
    ps[i] = v;
}

__global__ void meta_kernel(const int* __restrict__ path_ids, const int* __restrict__ seqp,
                            const int* __restrict__ seql, int* __restrict__ start,
                            int* __restrict__ lenp, int* __restrict__ lcount, int E){
    int e = blockIdx.x * blockDim.x + threadIdx.x;
    if (e >= E) return;
    int p = path_ids[e];
    int s = seqp[e];
    if (s == 0) start[p] = e;
    if (e == E - 1 || path_ids[e + 1] != p) lenp[p] = s + 1;
    atomicAdd(&lcount[seql[e]], 1);
}

__global__ void bhist_block_kernel(const int* __restrict__ lenp, int* __restrict__ bcnt,
                                   int* __restrict__ bh, int n_paths){
    __shared__ int h[16];
    if (threadIdx.x < 16) h[threadIdx.x] = 0;
    __syncthreads();
    int p = blockIdx.x * 256 + threadIdx.x;
    if (p < n_paths) atomicAdd(&h[lenp[p] - 1], 1);
    __syncthreads();
    if (threadIdx.x < 16){
        bh[blockIdx.x * 16 + threadIdx.x] = h[threadIdx.x];
        atomicAdd(&bcnt[threadIdx.x], h[threadIdx.x]);
    }
}

__global__ void bscan2_kernel(const int* __restrict__ bcnt, const int* __restrict__ bh,
                              int* __restrict__ bb, int nblk){
    __shared__ int base[16];
    if (threadIdx.x == 0){
        int run = 0;
        for (int i = 0; i < 16; i++){ base[i] = run; run += bcnt[i]; }
    }
    __syncthreads();
    int i = threadIdx.x;
    if (i < 16){
        int run = base[i];
        for (int blk = 0; blk < nblk; ++blk){
            bb[blk * 16 + i] = run;
            run += bh[blk * 16 + i];
        }
    }
}

__global__ void bscatter2_kernel(const int* __restrict__ lenp, const int* __restrict__ bb,
                                 int* __restrict__ order, int n_paths){
    __shared__ int h[16];
    if (threadIdx.x < 16) h[threadIdx.x] = 0;
    __syncthreads();
    int p = blockIdx.x * 256 + threadIdx.x;
    if (p < n_paths){
        int b = lenp[p] - 1;
        int r = atomicAdd(&h[b], 1);
        order[bb[blockIdx.x * 16 + b] + r] = p;
    }
}

__global__ __launch_bounds__(1024) void scan_kernel(const int* __restrict__ cnt, int* __restrict__ off, int n){
    __shared__ int psh[1025];
    int tid = threadIdx.x;
    int chunk = (n + 1023) / 1024;
    int b = tid * chunk, e = min(b + chunk, n);
    int s = 0;
    for (int i = b; i < e; ++i) s += cnt[i];
    psh[tid + 1] = s;
    if (tid == 0) psh[0] = 0;
    __syncthreads();
    for (int ofs = 1; ofs < 1024; ofs <<= 1){
        int v = (tid + 1 >= ofs) ? psh[tid + 1 - ofs] : 0;
        __syncthreads();
        psh[tid + 1] += v;
        __syncthreads();
    }
    int run = psh[tid];
    for (int i = b; i < e; ++i){ off[i] = run; run += cnt[i]; }
    if (b < n && e == n) off[n] = run;
}

__global__ void fillpbl_kernel(const int* __restrict__ seql, const int* __restrict__ p2l,
                               const int* __restrict__ loff, int* __restrict__ lfill,
                               int* __restrict__ pbl, int E){
    int e = blockIdx.x * blockDim.x + threadIdx.x;
    if (e >= E) return;
    int l = seql[e];
    int pos = loff[l] + atomicAdd(&lfill[l], 1);
    pbl[pos] = p2l[e];
}

// pack GRU weight B-fragments (hi/lo): ((mat*6 + jt)*64 + lane)*8 + i ; mat: 0=pK 1=pRK 2=lK 3=lRK
__global__ void pack_gru_kernel(const float* __restrict__ pK, const float* __restrict__ pRK,
                                const float* __restrict__ lK, const float* __restrict__ lRK,
                                short* __restrict__ th, short* __restrict__ tl){
    int t = blockIdx.x * blockDim.x + threadIdx.x;
    if (t >= 4 * 6 * 64) return;
    int lane = t & 63;
    int jt = (t >> 6) % 6;
    int mat = t / (6 * 64);
    const float* W = (mat == 0) ? pK : (mat == 1) ? pRK : (mat == 2) ? lK : lRK;
    int n = lane & 15, g = lane >> 4;
    for (int i = 0; i < 8; i++){
        float w = W[(g * 8 + i) * GG + jt * 16 + n];
        short hi, lo; split2(w, hi, lo);
        th[(size_t)t * 8 + i] = hi;
        tl[(size_t)t * 8 + i] = lo;
    }
}

__global__ void pack_readout_kernel(const float* __restrict__ w1, const float* __restrict__ w2,
                                    short* __restrict__ th, short* __restrict__ tl){
    int t = blockIdx.x * blockDim.x + threadIdx.x;
    if (t >= 144 * 64) return;
    int lane = t & 63;
    int f = t >> 6;
    int n = lane & 15, g = lane >> 4;
    for (int i = 0; i < 8; i++){
        float w;
        if (f < 16) w = w1[(g * 8 + i) * 256 + f * 16 + n];
        else {
            int ff = f - 16, kc = ff >> 4, jt = ff & 15;
            w = w2[(kc * 32 + g * 8 + i) * 256 + jt * 16 + n];
        }
        short hi, lo; split2(w, hi, lo);
        th[(size_t)t * 8 + i] = hi;
        tl[(size_t)t * 8 + i] = lo;
    }
}

// ---------------- MFMA GRU pieces ----------------
template<bool MASK>
__device__ __forceinline__ void gru_gates(const f32x4 accZR[4], const f32x4 accXC[2], const f32x4 accHC[2],
                                          float hD[2][4], const int lenD[4], int t)
{
    #pragma unroll
    for (int tt = 0; tt < 2; tt++){
        #pragma unroll
        for (int r = 0; r < 4; r++){
            float z = fsig(accZR[tt][r]);
            float rr = fsig(accZR[2 + tt][r]);
            float c = ftanh(accXC[tt][r] + rr * accHC[tt][r]);
            float hn = z * hD[tt][r] + (1.0f - z) * c;
            if (MASK) hD[tt][r] = (t < lenD[r]) ? hn : hD[tt][r];
            else      hD[tt][r] = hn;
        }
    }
}

__device__ __forceinline__ void load_wfrags(const short* __restrict__ gth, const short* __restrict__ gtl,
                                            int matA, int matB, int lane,
                                            bf16x8 wKh[6], bf16x8 wKl[6], bf16x8 wRKh[6], bf16x8 wRKl[6]){
    #pragma unroll
    for (int jt = 0; jt < 6; jt++){
        wKh[jt]  = *(const bf16x8*)(gth + ((size_t)((matA * 6 + jt) * 64 + lane)) * 8);
        wKl[jt]  = *(const bf16x8*)(gtl + ((size_t)((matA * 6 + jt) * 64 + lane)) * 8);
        wRKh[jt] = *(const bf16x8*)(gth + ((size_t)((matB * 6 + jt) * 64 + lane)) * 8);
        wRKl[jt] = *(const bf16x8*)(gtl + ((size_t)((matB * 6 + jt) * 64 + lane)) * 8);
    }
}

__device__ __forceinline__ void load_biases(const float* __restrict__ bias, int l15,
                                            float bzr[4], float bx2[2], float bh2[2]){
    #pragma unroll
    for (int jt = 0; jt < 4; jt++) bzr[jt] = bias[jt * 16 + l15] + bias[GG + jt * 16 + l15];
    #pragma unroll
    for (int u = 0; u < 2; u++){
        bx2[u] = bias[(4 + u) * 16 + l15];
        bh2[u] = bias[GG + (4 + u) * 16 + l15];
    }
}

// ---------------- persistent cooperative MP kernel: 8 x (path phase | link phase) ----------------
// NOTE: NO min-waves clamp in launch_bounds — the per-phase live set is ~200 VGPR
// (96-VGPR weight fragments + accumulators). Clamping to 128 (R8: __launch_bounds__(512,2))
// caused scratch spills: FETCH 499MB/dispatch, MfmaUtil 4.6%. 512-thread block =>
// compiler caps at 256 VGPR, 1 block/CU, 256 blocks co-resident (coop launch valid).
__global__ __launch_bounds__(512) void mp_kernel(
    float* __restrict__ ps, float* __restrict__ ls,
    short* __restrict__ lsbh, short* __restrict__ lsbl,
    const int* __restrict__ l2p, const int* __restrict__ start,
    const int* __restrict__ lenp, const int* __restrict__ order,
    const int* __restrict__ loff, const int* __restrict__ pbl,
    const short* __restrict__ gth, const short* __restrict__ gtl,
    const float* __restrict__ pB, const float* __restrict__ lB,
    int n_paths, int n_links, int n_pchunks, int n_lchunks)
{
    cooperative_groups::grid_group grid = cooperative_groups::this_grid();
    __shared__ __align__(16) float hlds[8][16 * 36];

    int tid = threadIdx.x;
    int warp = tid >> 6;
    int lane = tid & 63;
    int l15 = lane & 15, g = lane >> 4;
    int gw = blockIdx.x * 8 + warp;
    int nw = gridDim.x * 8;
    float* hl = hlds[warp];

    for (int it = 0; it < 8; ++it){
        // ======== path phase ========
        {
            // prevent LICM from hoisting BOTH phases' weight sets out of the it-loop
            asm volatile("" ::: "memory");
            bf16x8 wKh[6], wKl[6], wRKh[6], wRKl[6];
            load_wfrags(gth, gtl, 0, 1, lane, wKh, wKl, wRKh, wRKl);
            float bzr[4], bx2[2], bh2[2];
            load_biases(pB, l15, bzr, bx2, bh2);

            for (int pass = 0;; ++pass){
                long long cc = (long long)pass * nw;
                if (cc >= n_pchunks) break;
                int c = (int)cc + ((pass & 1) ? (nw - 1 - gw) : gw);   // serpentine balance
                if (c >= n_pchunks) continue;
                int base16 = c * 16;

                int aidx = base16 + l15;
                int pa = order[min(aidx, n_paths - 1)];
                int s0 = start[pa];
                int la_c = lenp[pa];
                int la = (aidx < n_paths) ? la_c : 0;
                int maxlen = __shfl(la_c, 15);

                int pD[4], lenD[4]; bool vD[4];
                #pragma unroll
                for (int r = 0; r < 4; r++){
                    int di = base16 + g * 4 + r;
                    vD[r] = (di < n_paths);
                    pD[r] = order[min(di, n_paths - 1)];
                    lenD[r] = vD[r] ? lenp[pD[r]] : 0;
                }

                float hD[2][4];
                #pragma unroll
                for (int tt = 0; tt < 2; tt++)
                    #pragma unroll
                    for (int r = 0; r < 4; r++)
                        hD[tt][r] = ps[(size_t)pD[r] * DD + l15 + tt * 16];

                bf16x8 hfh, hfl;
                {
                    const float* hp = ps + (size_t)pa * DD + g * 8;
                    #pragma unroll
                    for (int i = 0; i < 8; i++){ short hi, lo; split2(hp[i], hi, lo); hfh[i] = hi; hfl[i] = lo; }
                }

                bf16x8 xfh, xfl;
                {
                    int lk = l2p[s0];
                    xfh = *reinterpret_cast<const bf16x8*>(lsbh + (size_t)lk * DD + g * 8);
                    xfl = *reinterpret_cast<const bf16x8*>(lsbl + (size_t)lk * DD + g * 8);
                }

                for (int t = 0; t < maxlen; ++t){
                    bf16x8 nxh, nxl;
                    int tn = t + 1;
                    if (tn < maxlen){
                        int e = s0 + max(min(tn, la - 1), 0);
                        int lk = l2p[e];
                        nxh = *reinterpret_cast<const bf16x8*>(lsbh + (size_t)lk * DD + g * 8);
                        nxl = *reinterpret_cast<const bf16x8*>(lsbl + (size_t)lk * DD + g * 8);
                    }

                    f32x4 accZR[4], accXC[2], accHC[2];
                    #pragma unroll
                    for (int jt = 0; jt < 4; jt++){
                        f32x4 a = splat4(bzr[jt]);
                        MFMA3(a, xfh, xfl, wKh[jt],  wKl[jt]);
                        MFMA3(a, hfh, hfl, wRKh[jt], wRKl[jt]);
                        accZR[jt] = a;
                    }
                    #pragma unroll
                    for (int u = 0; u < 2; u++){
                        f32x4 ax = splat4(bx2[u]);
                        MFMA3(ax, xfh, xfl, wKh[4 + u], wKl[4 + u]);
                        accXC[u] = ax;
                        f32x4 ah = splat4(bh2[u]);
                        MFMA3(ah, hfh, hfl, wRKh[4 + u], wRKl[4 + u]);
                        accHC[u] = ah;
                    }

                    gru_gates<true>(accZR, accXC, accHC, hD, lenD, t);

                    #pragma unroll
                    for (int tt = 0; tt < 2; tt++)
                        #pragma unroll
                        for (int r = 0; r < 4; r++)
                            hl[(g * 4 + r) * 36 + l15 + tt * 16] = hD[tt][r];
                    const float* hrow = hl + l15 * 36 + g * 8;
                    #pragma unroll
                    for (int i = 0; i < 8; i++){ short hi, lo; split2(hrow[i], hi, lo); hfh[i] = hi; hfl[i] = lo; }

                    xfh = nxh; xfl = nxl;
                }

                #pragma unroll
                for (int r = 0; r < 4; r++){
                    if (vD[r]){
                        #pragma unroll
                        for (int tt = 0; tt < 2; tt++)
                            ps[(size_t)pD[r] * DD + l15 + tt * 16] = hD[tt][r];
                    }
                }
            }
        }
        __threadfence();
        grid.sync();

        // ======== link phase (fused segment-sum + link GRU) ========
        {
            asm volatile("" ::: "memory");
            bf16x8 wKh[6], wKl[6], wRKh[6], wRKl[6];
            load_wfrags(gth, gtl, 2, 3, lane, wKh, wKl, wRKh, wRKl);
            float bzr[4], bx2[2], bh2[2];
            load_biases(lB, l15, bzr, bx2, bh2);

            for (int c = gw; c < n_lchunks; c += nw){
                int base16 = c * 16;
                int pa = min(base16 + l15, n_links - 1);

                float4 s0v = {0,0,0,0}, s1v = {0,0,0,0};
                {
                    int b = loff[pa], e = loff[pa + 1];
                    #pragma unroll 4
                    for (int k = b; k < e; ++k){
                        const float4* pr = (const float4*)(ps + (size_t)pbl[k] * DD) + g * 2;
                        float4 v0 = pr[0], v1 = pr[1];
                        s0v.x += v0.x; s0v.y += v0.y; s0v.z += v0.z; s0v.w += v0.w;
                        s1v.x += v1.x; s1v.y += v1.y; s1v.z += v1.z; s1v.w += v1.w;
                    }
                }

                int pD[4]; bool vD[4]; int lenD[4];
                #pragma unroll
                for (int r = 0; r < 4; r++){
                    int di = base16 + g * 4 + r;
                    vD[r] = (di < n_links);
                    pD[r] = min(di, n_links - 1);
                    lenD[r] = 0;
                }

                float hD[2][4];
                #pragma unroll
                for (int tt = 0; tt < 2; tt++)
                    #pragma unroll
                    for (int r = 0; r < 4; r++)
                        hD[tt][r] = ls[(size_t)pD[r] * DD + l15 + tt * 16];

                bf16x8 hfh, hfl, xfh, xfl;
                {
                    const float* hp = ls + (size_t)pa * DD + g * 8;
                    float xs[8] = { s0v.x, s0v.y, s0v.z, s0v.w, s1v.x, s1v.y, s1v.z, s1v.w };
                    #pragma unroll
                    for (int i = 0; i < 8; i++){
                        short hi, lo;
                        split2(hp[i], hi, lo); hfh[i] = hi; hfl[i] = lo;
                        split2(xs[i], hi, lo); xfh[i] = hi; xfl[i] = lo;
                    }
                }

                f32x4 accZR[4], accXC[2], accHC[2];
                #pragma unroll
                for (int jt = 0; jt < 4; jt++){
                    f32x4 a = splat4(bzr[jt]);
                    MFMA3(a, xfh, xfl, wKh[jt],  wKl[jt]);
                    MFMA3(a, hfh, hfl, wRKh[jt], wRKl[jt]);
                    accZR[jt] = a;
                }
                #pragma unroll
                for (int u = 0; u < 2; u++){
                    f32x4 ax = splat4(bx2[u]);
                    MFMA3(ax, xfh, xfl, wKh[4 + u], wKl[4 + u]);
                    accXC[u] = ax;
                    f32x4 ah = splat4(bh2[u]);
                    MFMA3(ah, hfh, hfl, wRKh[4 + u], wRKl[4 + u]);
                    accHC[u] = ah;
                }
                gru_gates<false>(accZR, accXC, accHC, hD, lenD, 0);

                #pragma unroll
                for (int r = 0; r < 4; r++){
                    if (vD[r]){
                        #pragma unroll
                        for (int tt = 0; tt < 2; tt++){
                            float v = hD[tt][r];
                            size_t off = (size_t)pD[r] * DD + l15 + tt * 16;
                            ls[off] = v;
                            short hi, lo; split2(v, hi, lo);
                            lsbh[off] = hi; lsbl[off] = lo;
                        }
                    }
                }
            }
        }
        __threadfence();
        grid.sync();
    }
}

// ---------------- readout MLP (MFMA split-bf16): 32 -> 256 relu -> 256 relu -> 1 ----------------
__global__ __launch_bounds__(256) void readout_kernel(
    const float* __restrict__ ps,
    const short* __restrict__ rth, const short* __restrict__ rtl,
    const float* __restrict__ b1, const float* __restrict__ b2,
    const float* __restrict__ w3, const float* __restrict__ b3,
    float* __restrict__ out, int n_paths)
{
    __shared__ __align__(16) float hT[4][16 * 68];

    int tid = threadIdx.x;
    int warp = tid >> 6;
    int lane = tid & 63;
    int l15 = lane & 15, g = lane >> 4;
    int pbase = blockIdx.x * 64 + warp * 16;

    bf16x8 xh, xl;
    {
        int prow = min(pbase + l15, n_paths - 1);
        const float* xp = ps + (size_t)prow * DD + g * 8;
        #pragma unroll
        for (int i = 0; i < 8; i++){ short hi, lo; split2(xp[i], hi, lo); xh[i] = hi; xl[i] = lo; }
    }

    float* hw = hT[warp];

    f32x4 acc2[16];
    #pragma unroll
    for (int jt = 0; jt < 16; jt++) acc2[jt] = splat4(b2[jt * 16 + l15]);

    #pragma unroll 1
    for (int c = 0; c < 4; c++){
        #pragma unroll
        for (int u = 0; u < 4; u++){
            int jt = c * 4 + u;
            bf16x8 wh = *(const bf16x8*)(rth + (size_t)(jt * 64 + lane) * 8);
            bf16x8 wl = *(const bf16x8*)(rtl + (size_t)(jt * 64 + lane) * 8);
            f32x4 a = splat4(b1[jt * 16 + l15]);
            MFMA3(a, xh, xl, wh, wl);
            #pragma unroll
            for (int r = 0; r < 4; r++)
                hw[(g * 4 + r) * 68 + u * 16 + l15] = fmaxf(a[r], 0.0f);
        }
        bf16x8 ah[2], al[2];
        #pragma unroll
        for (int kc2 = 0; kc2 < 2; kc2++){
            const float* hr = hw + l15 * 68 + kc2 * 32 + g * 8;
            #pragma unroll
            for (int i = 0; i < 8; i++){ short hi, lo; split2(hr[i], hi, lo); ah[kc2][i] = hi; al[kc2][i] = lo; }
        }
        #pragma unroll
        for (int jt = 0; jt < 16; jt++){
            #pragma unroll
            for (int kc2 = 0; kc2 < 2; kc2++){
                int f = 16 + (c * 2 + kc2) * 16 + jt;
                bf16x8 wh = *(const bf16x8*)(rth + (size_t)(f * 64 + lane) * 8);
                bf16x8 wl = *(const bf16x8*)(rtl + (size_t)(f * 64 + lane) * 8);
                MFMA3(acc2[jt], ah[kc2], al[kc2], wh, wl);
            }
        }
    }

    float part[4] = {0.0f, 0.0f, 0.0f, 0.0f};
    #pragma unroll
    for (int jt = 0; jt < 16; jt++){
        float w3v = w3[jt * 16 + l15];
        #pragma unroll
        for (int r = 0; r < 4; r++)
            part[r] = fmaf(fmaxf(acc2[jt][r], 0.0f), w3v, part[r]);
    }
    #pragma unroll
    for (int ofs = 1; ofs < 16; ofs <<= 1)
        #pragma unroll
        for (int r = 0; r < 4; r++)
            part[r] += __shfl_xor(part[r], ofs);

    if (l15 == 0){
        float b3v = b3[0];
        #pragma unroll
        for (int r = 0; r < 4; r++){
            int p = pbase + g * 4 + r;
            if (p < n_paths) out[p] = part[r] + b3v;
        }
    }
}

extern "C" void kernel_launch(void* const* d_in, const int* in_sizes, int n_in,
                              void* d_out, int out_size, void* d_ws, size_t ws_size,
                              hipStream_t stream)
{
    const float* capacity = (const float*)d_in[0];
    const float* traffic  = (const float*)d_in[1];
    const float* packets  = (const float*)d_in[2];
    const float* tdp      = (const float*)d_in[3];
    const float* pK  = (const float*)d_in[4];
    const float* pRK = (const float*)d_in[5];
    const float* pB  = (const float*)d_in[6];
    const float* lK  = (const float*)d_in[7];
    const float* lRK = (const float*)d_in[8];
    const float* lB  = (const float*)d_in[9];
    const float* w1  = (const float*)d_in[10];
    const float* b1  = (const float*)d_in[11];
    const float* w2  = (const float*)d_in[12];
    const float* b2  = (const float*)d_in[13];
    const float* w3  = (const float*)d_in[14];
    const float* b3  = (const float*)d_in[15];
    const int* l2p      = (const int*)d_in[16];
    const int* path_ids = (const int*)d_in[17];
    const int* seqp     = (const int*)d_in[18];
    const int* p2l      = (const int*)d_in[19];
    const int* seql     = (const int*)d_in[20];
    int n_links = in_sizes[0];
    int n_paths = in_sizes[1];
    int E       = in_sizes[16];
    float* out = (float*)d_out;

    char* w = (char*)d_ws;
    auto carve = [&](size_t bytes) -> void* {
        void* r = (void*)w;
        w += (bytes + 255) & ~(size_t)255;
        return r;
    };
    int nblk = (n_paths + 255) / 256;
    float* ls    = (float*)carve((size_t)n_links * DD * 4);
    short* lsbh  = (short*)carve((size_t)n_links * DD * 2);
    short* lsbl  = (short*)carve((size_t)n_links * DD * 2);
    float* ps    = (float*)carve((size_t)n_paths * DD * 4);
    int* start   = (int*)carve((size_t)n_paths * 4);
    int* lenp    = (int*)carve((size_t)n_paths * 4);
    int* order   = (int*)carve((size_t)n_paths * 4);
    int* loff    = (int*)carve((size_t)(n_links + 1) * 4);
    int* pbl     = (int*)carve((size_t)E * 4);
    short* gth   = (short*)carve((size_t)4 * 6 * 64 * 8 * 2);
    short* gtl   = (short*)carve((size_t)4 * 6 * 64 * 8 * 2);
    short* rth   = (short*)carve((size_t)144 * 64 * 8 * 2);
    short* rtl   = (short*)carve((size_t)144 * 64 * 8 * 2);
    int* bh      = (int*)carve((size_t)nblk * 16 * 4);
    int* bb      = (int*)carve((size_t)nblk * 16 * 4);
    int* izero   = (int*)carve(((size_t)2 * n_links + 16) * 4);
    int* lcount  = izero;
    int* lfill   = izero + n_links;
    int* bcnt    = izero + 2 * n_links;

    const int TB = 256;
    int nz = 2 * n_links + 16;
    zero_ints_kernel<<<(nz + TB - 1) / TB, TB, 0, stream>>>(izero, nz);
    init_link_kernel<<<(n_links * DD + TB - 1) / TB, TB, 0, stream>>>(capacity, ls, lsbh, lsbl, n_links);
    init_path_kernel<<<(n_paths * DD + TB - 1) / TB, TB, 0, stream>>>(traffic, packets, tdp, ps, n_paths);
    meta_kernel<<<(E + TB - 1) / TB, TB, 0, stream>>>(path_ids, seqp, seql, start, lenp, lcount, E);
    bhist_block_kernel<<<nblk, 256, 0, stream>>>(lenp, bcnt, bh, n_paths);
    bscan2_kernel<<<1, 64, 0, stream>>>(bcnt, bh, bb, nblk);
    bscatter2_kernel<<<nblk, 256, 0, stream>>>(lenp, bb, order, n_paths);
    scan_kernel<<<1, 1024, 0, stream>>>(lcount, loff, n_links);
    fillpbl_kernel<<<(E + TB - 1) / TB, TB, 0, stream>>>(seql, p2l, loff, lfill, pbl, E);
    pack_gru_kernel<<<(4 * 6 * 64 + TB - 1) / TB, TB, 0, stream>>>(pK, pRK, lK, lRK, gth, gtl);
    pack_readout_kernel<<<(144 * 64 + TB - 1) / TB, TB, 0, stream>>>(w1, w2, rth, rtl);

    int n_pchunks = (n_paths + 15) / 16;
    int n_lchunks = (n_links + 15) / 16;

    {
        void* params[] = {
            &ps, &ls, &lsbh, &lsbl,
            (void*)&l2p, (void*)&start, (void*)&lenp, (void*)&order,
            (void*)&loff, (void*)&pbl, (void*)&gth, (void*)&gtl,
            (void*)&pB, (void*)&lB,
            &n_paths, &n_links, &n_pchunks, &n_lchunks
        };
        hipLaunchCooperativeKernel((const void*)mp_kernel, dim3(256), dim3(512),
                                   params, 0, stream);
    }

    readout_kernel<<<(n_paths + 63) / 64, 256, 0, stream>>>(ps, rth, rtl, b1, b2, w3, b3, out, n_paths);
}

// Round 10
// 1187.537 us; speedup vs baseline: 2.1197x; 2.1197x over previous
//
#include <hip/hip_runtime.h>
#include <hip/hip_bf16.h>

#define DD 32
#define GG 96   // 3*DD

typedef __attribute__((ext_vector_type(8))) short bf16x8;
typedef __attribute__((ext_vector_type(4))) float f32x4;

__device__ __forceinline__ float frcp(float x){ return __builtin_amdgcn_rcpf(x); }
__device__ __forceinline__ float fsig(float x){
    float e = __expf(-x);
    return frcp(1.0f + e);
}
__device__ __forceinline__ float ftanh(float x){
    float ax = fabsf(x);
    float e  = __expf(-2.0f * ax);
    float t  = (1.0f - e) * frcp(1.0f + e);
    return copysignf(t, x);
}
__device__ __forceinline__ short f2bf(float f){
    union { float f; unsigned u; } v; v.f = f;
    unsigned r = v.u + 0x7fffu + ((v.u >> 16) & 1u);   // RNE
    return (short)(r >> 16);
}
__device__ __forceinline__ float bf2f(short s){
    union { unsigned u; float f; } v; v.u = ((unsigned)(unsigned short)s) << 16;
    return v.f;
}
__device__ __forceinline__ void split2(float x, short& hi, short& lo){
    hi = f2bf(x);
    lo = f2bf(x - bf2f(hi));
}
__device__ __forceinline__ f32x4 splat4(float x){ f32x4 v = { x, x, x, x }; return v; }

#define MFMA3(acc, ah, al, bh, bl) do { \
    acc = __builtin_amdgcn_mfma_f32_16x16x32_bf16(ah, bh, acc, 0, 0, 0); \
    acc = __builtin_amdgcn_mfma_f32_16x16x32_bf16(al, bh, acc, 0, 0, 0); \
    acc = __builtin_amdgcn_mfma_f32_16x16x32_bf16(ah, bl, acc, 0, 0, 0); \
} while (0)

// ---------------- setup kernels ----------------

__global__ void zero_ints_kernel(int* a, int n){
    int i = blockIdx.x * blockDim.x + threadIdx.x;
    if (i < n) a[i] = 0;
}

// fused init of link state (f32 + hi/lo bf16 mirrors) and path state
__global__ void init_states_kernel(const float* __restrict__ cap,
                                   const float* __restrict__ traffic, const float* __restrict__ packets,
                                   const float* __restrict__ tdp,
                                   float* __restrict__ ls, short* __restrict__ lsbh, short* __restrict__ lsbl,
                                   float* __restrict__ ps, int n_links, int n_paths){
    int i = blockIdx.x * blockDim.x + threadIdx.x;
    int nl = n_links * DD;
    if (i < nl){
        int l = i >> 5, d = i & 31;
        float v = (d == 0) ? cap[l] : 0.0f;
        ls[i] = v;
        short hi, lo; split2(v, hi, lo);
        lsbh[i] = hi; lsbl[i] = lo;
        return;
    }
    int j = i - nl;
    if (j >= n_paths * DD) return;
    int p = j >> 5, d = j & 31;
    float v = 0.0f;
    if (d == 0) v = traffic[p];
    else if (d == 1) v = packets[p];
    else if (d < 14) v = tdp[p * 12 + (d - 2)];
    ps[j] = v;
}

__global__ void meta_kernel(const int* __restrict__ path_ids, const int* __restrict__ seqp,
                            const int* __restrict__ seql, int* __restrict__ start,
                            int* __restrict__ lenp, int* __restrict__ lcount, int E){
    int e = blockIdx.x * blockDim.x + threadIdx.x;
    if (e >= E) return;
    int p = path_ids[e];
    int s = seqp[e];
    if (s == 0) start[p] = e;
    if (e == E - 1 || path_ids[e + 1] != p) lenp[p] = s + 1;
    atomicAdd(&lcount[seql[e]], 1);
}

__global__ void bhist_block_kernel(const int* __restrict__ lenp, int* __restrict__ bcnt,
                                   int* __restrict__ bh, int n_paths){
    __shared__ int h[16];
    if (threadIdx.x < 16) h[threadIdx.x] = 0;
    __syncthreads();
    int p = blockIdx.x * 256 + threadIdx.x;
    if (p < n_paths) atomicAdd(&h[lenp[p] - 1], 1);
    __syncthreads();
    if (threadIdx.x < 16){
        bh[blockIdx.x * 16 + threadIdx.x] = h[threadIdx.x];
        atomicAdd(&bcnt[threadIdx.x], h[threadIdx.x]);
    }
}

__global__ void bscan2_kernel(const int* __restrict__ bcnt, const int* __restrict__ bh,
                              int* __restrict__ bb, int nblk){
    __shared__ int base[16];
    if (threadIdx.x == 0){
        int run = 0;
        for (int i = 0; i < 16; i++){ base[i] = run; run += bcnt[i]; }
    }
    __syncthreads();
    int i = threadIdx.x;
    if (i < 16){
        int run = base[i];
        for (int blk = 0; blk < nblk; ++blk){
            bb[blk * 16 + i] = run;
            run += bh[blk * 16 + i];
        }
    }
}

__global__ void bscatter2_kernel(const int* __restrict__ lenp, const int* __restrict__ bb,
                                 int* __restrict__ order, int n_paths){
    __shared__ int h[16];
    if (threadIdx.x < 16) h[threadIdx.x] = 0;
    __syncthreads();
    int p = blockIdx.x * 256 + threadIdx.x;
    if (p < n_paths){
        int b = lenp[p] - 1;
        int r = atomicAdd(&h[b], 1);
        order[bb[blockIdx.x * 16 + b] + r] = p;
    }
}

__global__ __launch_bounds__(1024) void scan_kernel(const int* __restrict__ cnt, int* __restrict__ off, int n){
    __shared__ int psh[1025];
    int tid = threadIdx.x;
    int chunk = (n + 1023) / 1024;
    int b = tid * chunk, e = min(b + chunk, n);
    int s = 0;
    for (int i = b; i < e; ++i) s += cnt[i];
    psh[tid + 1] = s;
    if (tid == 0) psh[0] = 0;
    __syncthreads();
    for (int ofs = 1; ofs < 1024; ofs <<= 1){
        int v = (tid + 1 >= ofs) ? psh[tid + 1 - ofs] : 0;
        __syncthreads();
        psh[tid + 1] += v;
        __syncthreads();
    }
    int run = psh[tid];
    for (int i = b; i < e; ++i){ off[i] = run; run += cnt[i]; }
    if (b < n && e == n) off[n] = run;
}

__global__ void fillpbl_kernel(const int* __restrict__ seql, const int* __restrict__ p2l,
                               const int* __restrict__ loff, int* __restrict__ lfill,
                               int* __restrict__ pbl, int E){
    int e = blockIdx.x * blockDim.x + threadIdx.x;
    if (e >= E) return;
    int l = seql[e];
    int pos = loff[l] + atomicAdd(&lfill[l], 1);
    pbl[pos] = p2l[e];
}

// fused weight packing.
// GRU tables: ((mat*6 + jt)*64 + lane)*8 + i ; mat: 0=pK 1=pRK 2=lK 3=lRK
// readout tables: f<16 -> w1 tile f ; f>=16 -> w2 (kc=(f-16)>>4, jt=(f-16)&15)
__global__ void pack_all_kernel(const float* __restrict__ pK, const float* __restrict__ pRK,
                                const float* __restrict__ lK, const float* __restrict__ lRK,
                                const float* __restrict__ w1, const float* __restrict__ w2,
                                short* __restrict__ gth, short* __restrict__ gtl,
                                short* __restrict__ rth, short* __restrict__ rtl){
    int t0 = blockIdx.x * blockDim.x + threadIdx.x;
    if (t0 < 4 * 6 * 64){
        int t = t0;
        int lane = t & 63;
        int jt = (t >> 6) % 6;
        int mat = t / (6 * 64);
        const float* W = (mat == 0) ? pK : (mat == 1) ? pRK : (mat == 2) ? lK : lRK;
        int n = lane & 15, g = lane >> 4;
        for (int i = 0; i < 8; i++){
            float w = W[(g * 8 + i) * GG + jt * 16 + n];
            short hi, lo; split2(w, hi, lo);
            gth[(size_t)t * 8 + i] = hi;
            gtl[(size_t)t * 8 + i] = lo;
        }
        return;
    }
    int t = t0 - 4 * 6 * 64;
    if (t >= 144 * 64) return;
    int lane = t & 63;
    int f = t >> 6;
    int n = lane & 15, g = lane >> 4;
    for (int i = 0; i < 8; i++){
        float w;
        if (f < 16) w = w1[(g * 8 + i) * 256 + f * 16 + n];
        else {
            int ff = f - 16, kc = ff >> 4, jt = ff & 15;
            w = w2[(kc * 32 + g * 8 + i) * 256 + jt * 16 + n];
        }
        short hi, lo; split2(w, hi, lo);
        rth[(size_t)t * 8 + i] = hi;
        rtl[(size_t)t * 8 + i] = lo;
    }
}

// ---------------- MFMA GRU gates ----------------
// D-layout: lane col n=lane&15 (dim within 16-tile), rows = 4 paths (g*4+r).
template<bool MASK>
__device__ __forceinline__ void gru_gates(const f32x4 accZR[4], const f32x4 accXC[2], const f32x4 accHC[2],
                                          float hD[2][4], const int lenD[4], int t)
{
    #pragma unroll
    for (int tt = 0; tt < 2; tt++){
        #pragma unroll
        for (int r = 0; r < 4; r++){
            float z = fsig(accZR[tt][r]);
            float rr = fsig(accZR[2 + tt][r]);
            float c = ftanh(accXC[tt][r] + rr * accHC[tt][r]);
            float hn = z * hD[tt][r] + (1.0f - z) * c;
            if (MASK) hD[tt][r] = (t < lenD[r]) ? hn : hD[tt][r];
            else      hD[tt][r] = hn;
        }
    }
}

// ---------------- path GRU (MFMA split-bf16, 16 paths/wave, persistent multi-chunk) ----------------
// NOTE: (256,1) — explicitly grant full register budget. Live set ~200 VGPR
// (96-VGPR weight fragments + accs). Any occupancy clamp (R6: ,3 / R8: ,2)
// capped VGPRs and produced 100+MB/dispatch scratch-spill traffic.
__global__ __launch_bounds__(256, 1) void path_gru_kernel(
    const short* __restrict__ lsbh, const short* __restrict__ lsbl, float* __restrict__ ps,
    const int* __restrict__ l2p, const int* __restrict__ start,
    const int* __restrict__ lenp, const int* __restrict__ order,
    const short* __restrict__ gth, const short* __restrict__ gtl,
    const float* __restrict__ bias, int n_paths, int n_waves, int stride)
{
    __shared__ __align__(16) float hlds[4][16 * 36];

    int tid = threadIdx.x;
    int warp = tid >> 6;
    int lane = tid & 63;
    int l15 = lane & 15, g = lane >> 4;

    int gw = blockIdx.x * 4 + warp;
    int nw = gridDim.x * 4;
    float* hl = hlds[warp];

    // weight fragments from packed table (coalesced b128 loads) — loaded once per wave
    bf16x8 wKh[6], wKl[6], wRKh[6], wRKl[6];
    #pragma unroll
    for (int jt = 0; jt < 6; jt++){
        wKh[jt]  = *(const bf16x8*)(gth + ((size_t)((0 * 6 + jt) * 64 + lane)) * 8);
        wKl[jt]  = *(const bf16x8*)(gtl + ((size_t)((0 * 6 + jt) * 64 + lane)) * 8);
        wRKh[jt] = *(const bf16x8*)(gth + ((size_t)((1 * 6 + jt) * 64 + lane)) * 8);
        wRKl[jt] = *(const bf16x8*)(gtl + ((size_t)((1 * 6 + jt) * 64 + lane)) * 8);
    }
    float bzr[4], bx2[2], bh2[2];
    #pragma unroll
    for (int jt = 0; jt < 4; jt++) bzr[jt] = bias[jt * 16 + l15] + bias[GG + jt * 16 + l15];
    #pragma unroll
    for (int u = 0; u < 2; u++){
        bx2[u] = bias[(4 + u) * 16 + l15];
        bh2[u] = bias[GG + (4 + u) * 16 + l15];
    }

    for (int w = gw; w < n_waves; w += nw){
        long long wp = ((long long)w * stride) % n_waves;   // golden-stride chunk permutation
        int base16 = (int)wp * 16;

        // A-side path (row = l15)
        int aidx = base16 + l15;
        int pa = order[min(aidx, n_paths - 1)];
        int s0 = start[pa];
        int la_c = lenp[pa];
        int la = (aidx < n_paths) ? la_c : 0;
        int maxlen = __shfl(la_c, 15);

        // D-side paths (4 rows this lane covers)
        int pD[4], lenD[4]; bool vD[4];
        #pragma unroll
        for (int r = 0; r < 4; r++){
            int di = base16 + g * 4 + r;
            vD[r] = (di < n_paths);
            pD[r] = order[min(di, n_paths - 1)];
            lenD[r] = vD[r] ? lenp[pD[r]] : 0;
        }

        // h state: f32 in D-layout
        float hD[2][4];
        #pragma unroll
        for (int tt = 0; tt < 2; tt++)
            #pragma unroll
            for (int r = 0; r < 4; r++)
                hD[tt][r] = ps[(size_t)pD[r] * DD + l15 + tt * 16];

        // initial h A-fragment (hi/lo) straight from ps
        bf16x8 hfh, hfl;
        {
            const float* hp = ps + (size_t)pa * DD + g * 8;
            #pragma unroll
            for (int i = 0; i < 8; i++){ short hi, lo; split2(hp[i], hi, lo); hfh[i] = hi; hfl[i] = lo; }
        }

        // prefetch x for t=0
        bf16x8 xfh, xfl;
        {
            int lk = l2p[s0];
            xfh = *reinterpret_cast<const bf16x8*>(lsbh + (size_t)lk * DD + g * 8);
            xfl = *reinterpret_cast<const bf16x8*>(lsbl + (size_t)lk * DD + g * 8);
        }

        for (int t = 0; t < maxlen; ++t){
            // prefetch next step's x while this step computes
            bf16x8 nxh, nxl;
            int tn = t + 1;
            if (tn < maxlen){
                int e = s0 + max(min(tn, la - 1), 0);
                int lk = l2p[e];
                nxh = *reinterpret_cast<const bf16x8*>(lsbh + (size_t)lk * DD + g * 8);
                nxl = *reinterpret_cast<const bf16x8*>(lsbl + (size_t)lk * DD + g * 8);
            }

            f32x4 accZR[4], accXC[2], accHC[2];
            #pragma unroll
            for (int jt = 0; jt < 4; jt++){
                f32x4 a = splat4(bzr[jt]);
                MFMA3(a, xfh, xfl, wKh[jt],  wKl[jt]);
                MFMA3(a, hfh, hfl, wRKh[jt], wRKl[jt]);
                accZR[jt] = a;
            }
            #pragma unroll
            for (int u = 0; u < 2; u++){
                f32x4 ax = splat4(bx2[u]);
                MFMA3(ax, xfh, xfl, wKh[4 + u], wKl[4 + u]);
                accXC[u] = ax;
                f32x4 ah = splat4(bh2[u]);
                MFMA3(ah, hfh, hfl, wRKh[4 + u], wRKl[4 + u]);
                accHC[u] = ah;
            }

            gru_gates<true>(accZR, accXC, accHC, hD, lenD, t);

            // transpose h (D-layout f32) -> A-fragment (hi/lo bf16) via wave-private LDS
            #pragma unroll
            for (int tt = 0; tt < 2; tt++)
                #pragma unroll
                for (int r = 0; r < 4; r++)
                    hl[(g * 4 + r) * 36 + l15 + tt * 16] = hD[tt][r];
            const float* hrow = hl + l15 * 36 + g * 8;
            #pragma unroll
            for (int i = 0; i < 8; i++){ short hi, lo; split2(hrow[i], hi, lo); hfh[i] = hi; hfl[i] = lo; }

            xfh = nxh; xfl = nxl;
        }

        // store final h
        #pragma unroll
        for (int r = 0; r < 4; r++){
            if (vD[r]){
                #pragma unroll
                for (int tt = 0; tt < 2; tt++)
                    ps[(size_t)pD[r] * DD + l15 + tt * 16] = hD[tt][r];
            }
        }
    }
}

// ---------------- fused segment-sum + link GRU (MFMA split-bf16, 16 links/wave) ----------------
__global__ __launch_bounds__(256, 1) void link_fused_kernel(
    const float* __restrict__ ps, const int* __restrict__ loff, const int* __restrict__ pbl,
    float* __restrict__ ls, short* __restrict__ lsbh, short* __restrict__ lsbl,
    const short* __restrict__ gth, const short* __restrict__ gtl,
    const float* __restrict__ bias, int n_links)
{
    int tid = threadIdx.x;
    int warp = tid >> 6;
    int lane = tid & 63;
    int l15 = lane & 15, g = lane >> 4;

    int base16 = (blockIdx.x * 4 + warp) * 16;
    if (base16 >= n_links) return;

    bf16x8 wKh[6], wKl[6], wRKh[6], wRKl[6];
    #pragma unroll
    for (int jt = 0; jt < 6; jt++){
        wKh[jt]  = *(const bf16x8*)(gth + ((size_t)((2 * 6 + jt) * 64 + lane)) * 8);
        wKl[jt]  = *(const bf16x8*)(gtl + ((size_t)((2 * 6 + jt) * 64 + lane)) * 8);
        wRKh[jt] = *(const bf16x8*)(gth + ((size_t)((3 * 6 + jt) * 64 + lane)) * 8);
        wRKl[jt] = *(const bf16x8*)(gtl + ((size_t)((3 * 6 + jt) * 64 + lane)) * 8);
    }
    float bzr[4], bx2[2], bh2[2];
    #pragma unroll
    for (int jt = 0; jt < 4; jt++) bzr[jt] = bias[jt * 16 + l15] + bias[GG + jt * 16 + l15];
    #pragma unroll
    for (int u = 0; u < 2; u++){
        bx2[u] = bias[(4 + u) * 16 + l15];
        bh2[u] = bias[GG + (4 + u) * 16 + l15];
    }

    int pa = min(base16 + l15, n_links - 1);

    // inline segment sum: this lane's 8 dims (g*8..g*8+7) of psum[pa]
    float4 s0v = {0,0,0,0}, s1v = {0,0,0,0};
    {
        int b = loff[pa], e = loff[pa + 1];
        #pragma unroll 4
        for (int k = b; k < e; ++k){
            const float4* pr = (const float4*)(ps + (size_t)pbl[k] * DD) + g * 2;
            float4 v0 = pr[0], v1 = pr[1];
            s0v.x += v0.x; s0v.y += v0.y; s0v.z += v0.z; s0v.w += v0.w;
            s1v.x += v1.x; s1v.y += v1.y; s1v.z += v1.z; s1v.w += v1.w;
        }
    }

    int pD[4]; bool vD[4]; int lenD[4];
    #pragma unroll
    for (int r = 0; r < 4; r++){
        int di = base16 + g * 4 + r;
        vD[r] = (di < n_links);
        pD[r] = min(di, n_links - 1);
        lenD[r] = 0;
    }

    float hD[2][4];
    #pragma unroll
    for (int tt = 0; tt < 2; tt++)
        #pragma unroll
        for (int r = 0; r < 4; r++)
            hD[tt][r] = ls[(size_t)pD[r] * DD + l15 + tt * 16];

    bf16x8 hfh, hfl, xfh, xfl;
    {
        const float* hp = ls + (size_t)pa * DD + g * 8;
        float xs[8] = { s0v.x, s0v.y, s0v.z, s0v.w, s1v.x, s1v.y, s1v.z, s1v.w };
        #pragma unroll
        for (int i = 0; i < 8; i++){
            short hi, lo;
            split2(hp[i], hi, lo); hfh[i] = hi; hfl[i] = lo;
            split2(xs[i], hi, lo); xfh[i] = hi; xfl[i] = lo;
        }
    }

    f32x4 accZR[4], accXC[2], accHC[2];
    #pragma unroll
    for (int jt = 0; jt < 4; jt++){
        f32x4 a = splat4(bzr[jt]);
        MFMA3(a, xfh, xfl, wKh[jt],  wKl[jt]);
        MFMA3(a, hfh, hfl, wRKh[jt], wRKl[jt]);
        accZR[jt] = a;
    }
    #pragma unroll
    for (int u = 0; u < 2; u++){
        f32x4 ax = splat4(bx2[u]);
        MFMA3(ax, xfh, xfl, wKh[4 + u], wKl[4 + u]);
        accXC[u] = ax;
        f32x4 ah = splat4(bh2[u]);
        MFMA3(ah, hfh, hfl, wRKh[4 + u], wRKl[4 + u]);
        accHC[u] = ah;
    }
    gru_gates<false>(accZR, accXC, accHC, hD, lenD, 0);

    #pragma unroll
    for (int r = 0; r < 4; r++){
        if (vD[r]){
            #pragma unroll
            for (int tt = 0; tt < 2; tt++){
                float v = hD[tt][r];
                size_t off = (size_t)pD[r] * DD + l15 + tt * 16;
                ls[off] = v;
                short hi, lo; split2(v, hi, lo);
                lsbh[off] = hi; lsbl[off] = lo;
            }
        }
    }
}

// ---------------- readout MLP (MFMA split-bf16): 32 -> 256 relu -> 256 relu -> 1 ----------------
__global__ __launch_bounds__(256) void readout_kernel(
    const float* __restrict__ ps,
    const short* __restrict__ rth, const short* __restrict__ rtl,
    const float* __restrict__ b1, const float* __restrict__ b2,
    const float* __restrict__ w3, const float* __restrict__ b3,
    float* __restrict__ out, int n_paths)
{
    __shared__ __align__(16) float hT[4][16 * 68];

    int tid = threadIdx.x;
    int warp = tid >> 6;
    int lane = tid & 63;
    int l15 = lane & 15, g = lane >> 4;
    int pbase = blockIdx.x * 64 + warp * 16;

    bf16x8 xh, xl;
    {
        int prow = min(pbase + l15, n_paths - 1);
        const float* xp = ps + (size_t)prow * DD + g * 8;
        #pragma unroll
        for (int i = 0; i < 8; i++){ short hi, lo; split2(xp[i], hi, lo); xh[i] = hi; xl[i] = lo; }
    }

    float* hw = hT[warp];

    f32x4 acc2[16];
    #pragma unroll
    for (int jt = 0; jt < 16; jt++) acc2[jt] = splat4(b2[jt * 16 + l15]);

    #pragma unroll 1
    for (int c = 0; c < 4; c++){
        #pragma unroll
        for (int u = 0; u < 4; u++){
            int jt = c * 4 + u;
            bf16x8 wh = *(const bf16x8*)(rth + (size_t)(jt * 64 + lane) * 8);
            bf16x8 wl = *(const bf16x8*)(rtl + (size_t)(jt * 64 + lane) * 8);
            f32x4 a = splat4(b1[jt * 16 + l15]);
            MFMA3(a, xh, xl, wh, wl);
            #pragma unroll
            for (int r = 0; r < 4; r++)
                hw[(g * 4 + r) * 68 + u * 16 + l15] = fmaxf(a[r], 0.0f);
        }
        bf16x8 ah[2], al[2];
        #pragma unroll
        for (int kc2 = 0; kc2 < 2; kc2++){
            const float* hr = hw + l15 * 68 + kc2 * 32 + g * 8;
            #pragma unroll
            for (int i = 0; i < 8; i++){ short hi, lo; split2(hr[i], hi, lo); ah[kc2][i] = hi; al[kc2][i] = lo; }
        }
        #pragma unroll
        for (int jt = 0; jt < 16; jt++){
            #pragma unroll
            for (int kc2 = 0; kc2 < 2; kc2++){
                int f = 16 + (c * 2 + kc2) * 16 + jt;
                bf16x8 wh = *(const bf16x8*)(rth + (size_t)(f * 64 + lane) * 8);
                bf16x8 wl = *(const bf16x8*)(rtl + (size_t)(f * 64 + lane) * 8);
                MFMA3(acc2[jt], ah[kc2], al[kc2], wh, wl);
            }
        }
    }

    float part[4] = {0.0f, 0.0f, 0.0f, 0.0f};
    #pragma unroll
    for (int jt = 0; jt < 16; jt++){
        float w3v = w3[jt * 16 + l15];
        #pragma unroll
        for (int r = 0; r < 4; r++)
            part[r] = fmaf(fmaxf(acc2[jt][r], 0.0f), w3v, part[r]);
    }
    #pragma unroll
    for (int ofs = 1; ofs < 16; ofs <<= 1)
        #pragma unroll
        for (int r = 0; r < 4; r++)
            part[r] += __shfl_xor(part[r], ofs);

    if (l15 == 0){
        float b3v = b3[0];
        #pragma unroll
        for (int r = 0; r < 4; r++){
            int p = pbase + g * 4 + r;
            if (p < n_paths) out[p] = part[r] + b3v;
        }
    }
}

static int host_gcd(int a, int b){ while (b){ int t = a % b; a = b; b = t; } return a; }

extern "C" void kernel_launch(void* const* d_in, const int* in_sizes, int n_in,
                              void* d_out, int out_size, void* d_ws, size_t ws_size,
                              hipStream_t stream)
{
    const float* capacity = (const float*)d_in[0];
    const float* traffic  = (const float*)d_in[1];
    const float* packets  = (const float*)d_in[2];
    const float* tdp      = (const float*)d_in[3];
    const float* pK  = (const float*)d_in[4];
    const float* pRK = (const float*)d_in[5];
    const float* pB  = (const float*)d_in[6];
    const float* lK  = (const float*)d_in[7];
    const float* lRK = (const float*)d_in[8];
    const float* lB  = (const float*)d_in[9];
    const float* w1  = (const float*)d_in[10];
    const float* b1  = (const float*)d_in[11];
    const float* w2  = (const float*)d_in[12];
    const float* b2  = (const float*)d_in[13];
    const float* w3  = (const float*)d_in[14];
    const float* b3  = (const float*)d_in[15];
    const int* l2p      = (const int*)d_in[16];
    const int* path_ids = (const int*)d_in[17];
    const int* seqp     = (const int*)d_in[18];
    const int* p2l      = (const int*)d_in[19];
    const int* seql     = (const int*)d_in[20];
    int n_links = in_sizes[0];
    int n_paths = in_sizes[1];
    int E       = in_sizes[16];
    float* out = (float*)d_out;

    char* w = (char*)d_ws;
    auto carve = [&](size_t bytes) -> void* {
        void* r = (void*)w;
        w += (bytes + 255) & ~(size_t)255;
        return r;
    };
    int nblk = (n_paths + 255) / 256;
    float* ls    = (float*)carve((size_t)n_links * DD * 4);
    short* lsbh  = (short*)carve((size_t)n_links * DD * 2);
    short* lsbl  = (short*)carve((size_t)n_links * DD * 2);
    float* ps    = (float*)carve((size_t)n_paths * DD * 4);
    int* start   = (int*)carve((size_t)n_paths * 4);
    int* lenp    = (int*)carve((size_t)n_paths * 4);
    int* order   = (int*)carve((size_t)n_paths * 4);
    int* loff    = (int*)carve((size_t)(n_links + 1) * 4);
    int* pbl     = (int*)carve((size_t)E * 4);
    short* gth   = (short*)carve((size_t)4 * 6 * 64 * 8 * 2);
    short* gtl   = (short*)carve((size_t)4 * 6 * 64 * 8 * 2);
    short* rth   = (short*)carve((size_t)144 * 64 * 8 * 2);
    short* rtl   = (short*)carve((size_t)144 * 64 * 8 * 2);
    int* bh      = (int*)carve((size_t)nblk * 16 * 4);
    int* bb      = (int*)carve((size_t)nblk * 16 * 4);
    int* izero   = (int*)carve(((size_t)2 * n_links + 16) * 4);
    int* lcount  = izero;
    int* lfill   = izero + n_links;
    int* bcnt    = izero + 2 * n_links;

    const int TB = 256;
    int nz = 2 * n_links + 16;
    zero_ints_kernel<<<(nz + TB - 1) / TB, TB, 0, stream>>>(izero, nz);
    init_states_kernel<<<(((n_links + n_paths) * DD) + TB - 1) / TB, TB, 0, stream>>>(
        capacity, traffic, packets, tdp, ls, lsbh, lsbl, ps, n_links, n_paths);
    meta_kernel<<<(E + TB - 1) / TB, TB, 0, stream>>>(path_ids, seqp, seql, start, lenp, lcount, E);
    bhist_block_kernel<<<nblk, 256, 0, stream>>>(lenp, bcnt, bh, n_paths);
    bscan2_kernel<<<1, 64, 0, stream>>>(bcnt, bh, bb, nblk);
    bscatter2_kernel<<<nblk, 256, 0, stream>>>(lenp, bb, order, n_paths);
    scan_kernel<<<1, 1024, 0, stream>>>(lcount, loff, n_links);
    fillpbl_kernel<<<(E + TB - 1) / TB, TB, 0, stream>>>(seql, p2l, loff, lfill, pbl, E);
    pack_all_kernel<<<((4 * 6 * 64 + 144 * 64) + TB - 1) / TB, TB, 0, stream>>>(
        pK, pRK, lK, lRK, w1, w2, gth, gtl, rth, rtl);

    int n_waves = (n_paths + 15) / 16;
    int stride = 1;
    if (n_waves > 2){
        stride = (int)((double)n_waves * 0.381966);
        if (stride < 1) stride = 1;
        while (host_gcd(stride, n_waves) != 1) stride++;
    }
    int pg_blocks = 512;                       // persistent: ~3 chunks per wave
    if (pg_blocks > (n_waves + 3) / 4) pg_blocks = (n_waves + 3) / 4;
    int lg_blocks = ((n_links + 15) / 16 + 3) / 4;

    for (int it = 0; it < 8; ++it){
        path_gru_kernel<<<pg_blocks, 256, 0, stream>>>(lsbh, lsbl, ps, l2p, start, lenp, order,
                                                       gth, gtl, pB, n_paths, n_waves, stride);
        link_fused_kernel<<<lg_blocks, 256, 0, stream>>>(ps, loff, pbl, ls, lsbh, lsbl,
                                                         gth, gtl, lB, n_links);
    }
    readout_kernel<<<(n_paths + 63) / 64, 256, 0, stream>>>(ps, rth, rtl, b1, b2, w3, b3, out, n_paths);
}